// Round 5
// baseline (360.365 us; speedup 1.0000x reference)
//
#include <hip/hip_runtime.h>
#include <math.h>

// Problem constants
#define BB 8
#define LL 512
#define UU 24
#define DD 1024
#define HH 16
#define DH 64
#define TT 72
#define CSKN 1024
#define NVOCAB 54945

typedef __attribute__((ext_vector_type(8))) short bf16x8;
typedef __attribute__((ext_vector_type(4))) float f32x4;

__device__ inline unsigned short f2b(float x) {
    unsigned u = __float_as_uint(x);
    unsigned r = u + 0x7FFFu + ((u >> 16) & 1u);
    return (unsigned short)(r >> 16);
}
__device__ inline unsigned pack2(float lo, float hi) {
    return (unsigned)f2b(lo) | ((unsigned)f2b(hi) << 16);
}
__device__ inline void dec8(uint2 c, float* cr) {
    cr[0] = (float)( c.x        & 0xff); cr[1] = (float)((c.x >>  8) & 0xff);
    cr[2] = (float)((c.x >> 16) & 0xff); cr[3] = (float)((c.x >> 24) & 0xff);
    cr[4] = (float)( c.y        & 0xff); cr[5] = (float)((c.y >>  8) & 0xff);
    cr[6] = (float)((c.y >> 16) & 0xff); cr[7] = (float)((c.y >> 24) & 0xff);
}

// ---------------------------------------------------------------------------
__global__ __launch_bounds__(256) void k_gather_cls(const float* __restrict__ hidden,
        const int* __restrict__ idx, float* __restrict__ sem_cls, float* __restrict__ trans_in)
{
    int bid = blockIdx.x; int b = bid / UU, u = bid % UU;
    int row = idx[b*UU + u];
    const float* src = hidden + ((size_t)(b*LL + row))*DD;
    float* d0 = trans_in + ((size_t)(b*TT + 3*u))*DD;
    float* sc = sem_cls + ((size_t)(b*UU + u))*DD;
    for (int d = threadIdx.x; d < DD; d += 256) {
        float v = src[d];
        sc[d] = v;
        d0[d] = v; d0[DD + d] = v; d0[2*DD + d] = v;
    }
}

__global__ void k_bn(const float* __restrict__ x, const float* __restrict__ g,
                     const float* __restrict__ be, const float* __restrict__ mu,
                     const float* __restrict__ var, float* __restrict__ y, int n)
{
    int i = blockIdx.x*256 + threadIdx.x;
    if (i >= n) return;
    int c = i % CSKN;
    y[i] = (x[i] - mu[c]) * (1.0f/sqrtf(var[c] + 1e-5f)) * g[c] + be[c];
}

// ---------------------------------------------------------------------------
// Double-buffered MFMA bf16 GEMM, 64x64 tile, 256 thr, 4 waves (2x2).
// EPI: 3 = gate-blend C=g*ep1+(1-g)*ep2, g=sigmoid(A@B+bias)
//      4 = csk: trans_in[b*72+3u+2][cc] += (A@B+bias), skip u==U-1 (C=trans_in)
template<int EPI>
__global__ __launch_bounds__(256) void mm64(
        const float* __restrict__ A1, const float* __restrict__ A2, int K1,
        const float* __restrict__ Bm, const float* __restrict__ bias,
        const float* __restrict__ ep1, const float* __restrict__ ep2,
        float* __restrict__ C, int N, int K)
{
    __shared__ __align__(16) unsigned short As[2][64][40];
    __shared__ __align__(16) unsigned short Bs[2][64][40];
    int tid = threadIdx.x;
    int wave = tid >> 6, lane = tid & 63;
    int l16 = lane & 15, g = lane >> 4;
    int wm = wave & 1, wn = wave >> 1;
    int row0 = blockIdx.y * 64, col0 = blockIdx.x * 64;

    int ar = tid >> 2, akq = (tid & 3) * 8;
    int bj0 = (tid & 31) * 2, bk0 = (tid >> 5) * 2;
    float4 a0, a1;
    float2 q00, q01, q10, q11;

    auto loadT = [&](int k0) {
        int kk = k0 + akq;
        const float* src = (kk < K1) ? A1 + (size_t)(row0+ar)*K1 + kk
                                     : A2 + (size_t)(row0+ar)*(K-K1) + (kk-K1);
        a0 = *(const float4*)src; a1 = *(const float4*)(src+4);
        const float* bs0 = Bm + (size_t)(k0 + bk0)*N + col0 + bj0;
        q00 = *(const float2*)bs0;       q01 = *(const float2*)(bs0 + N);
        const float* bs1 = bs0 + (size_t)16*N;
        q10 = *(const float2*)bs1;       q11 = *(const float2*)(bs1 + N);
    };
    auto storeT = [&](int buf) {
        unsigned* da = (unsigned*)&As[buf][ar][akq];
        da[0] = pack2(a0.x, a0.y); da[1] = pack2(a0.z, a0.w);
        da[2] = pack2(a1.x, a1.y); da[3] = pack2(a1.z, a1.w);
        *(unsigned*)&Bs[buf][bj0  ][bk0]    = pack2(q00.x, q01.x);
        *(unsigned*)&Bs[buf][bj0+1][bk0]    = pack2(q00.y, q01.y);
        *(unsigned*)&Bs[buf][bj0  ][bk0+16] = pack2(q10.x, q11.x);
        *(unsigned*)&Bs[buf][bj0+1][bk0+16] = pack2(q10.y, q11.y);
    };

    f32x4 acc[2][2] = {};
    loadT(0); storeT(0);
    __syncthreads();
    int nt = K / 32;
    for (int t = 0; t < nt; ++t) {
        int cur = t & 1;
        if (t + 1 < nt) loadT((t+1)*32);
        bf16x8 af[2], bfr[2];
        #pragma unroll
        for (int mf = 0; mf < 2; ++mf) af[mf] = *(const bf16x8*)&As[cur][wm*32 + mf*16 + l16][g*8];
        #pragma unroll
        for (int nf = 0; nf < 2; ++nf) bfr[nf] = *(const bf16x8*)&Bs[cur][wn*32 + nf*16 + l16][g*8];
        #pragma unroll
        for (int mf = 0; mf < 2; ++mf)
            #pragma unroll
            for (int nf = 0; nf < 2; ++nf)
                acc[mf][nf] = __builtin_amdgcn_mfma_f32_16x16x32_bf16(af[mf], bfr[nf], acc[mf][nf], 0, 0, 0);
        if (t + 1 < nt) storeT(cur ^ 1);
        __syncthreads();
    }
    #pragma unroll
    for (int mf = 0; mf < 2; ++mf)
        #pragma unroll
        for (int nf = 0; nf < 2; ++nf) {
            int cc = col0 + wn*32 + nf*16 + l16;
            float bv = bias[cc];
            #pragma unroll
            for (int r = 0; r < 4; ++r) {
                int rr = row0 + wm*32 + mf*16 + g*4 + r;
                float v = acc[mf][nf][r] + bv;
                if (EPI == 3) {
                    float gg = 1.0f/(1.0f + __expf(-v));
                    float tv = ep1[(size_t)rr*N + cc];
                    float iv = ep2[(size_t)rr*N + cc];
                    C[(size_t)rr*N + cc] = gg*tv + (1.0f - gg)*iv;
                } else { // EPI == 4
                    int bq = rr / UU, uq = rr % UU;
                    if (uq < UU-1) {
                        float* dst = &C[((size_t)(bq*TT + 3*uq + 2))*DD + cc];
                        *dst += v;
                    }
                }
            }
        }
}

// ---------------------------------------------------------------------------
// Fused Q/K/V projection, BM=64 BN=128, dbuf. Grid (24, 9); blockIdx.x>>3 selects.
__global__ __launch_bounds__(256) void mm_qkv(
        const float* __restrict__ x,
        const float* __restrict__ W0, const float* __restrict__ W1, const float* __restrict__ W2,
        const float* __restrict__ v0, const float* __restrict__ v1, const float* __restrict__ v2,
        float* __restrict__ C0, float* __restrict__ C1, float* __restrict__ C2)
{
    __shared__ __align__(16) unsigned short As[2][64][40];
    __shared__ __align__(16) unsigned short Bs[2][128][40];
    int which = blockIdx.x >> 3;
    int col0 = (blockIdx.x & 7) * 128;
    int row0 = blockIdx.y * 64;
    const float* W  = (which == 0) ? W0 : (which == 1) ? W1 : W2;
    const float* bb = (which == 0) ? v0 : (which == 1) ? v1 : v2;
    float*       C  = (which == 0) ? C0 : (which == 1) ? C1 : C2;
    int tid = threadIdx.x;
    int wave = tid >> 6, lane = tid & 63;
    int l16 = lane & 15, g = lane >> 4;
    int wm = wave & 1, wn = wave >> 1;

    int ar = tid >> 2, akq = (tid & 3) * 8;
    int bj0 = (tid & 63) * 2, ks = tid >> 6;   // 4 k-pair slots per thread
    float4 a0, a1;
    float2 b0[4], b1[4];

    auto loadT = [&](int k0) {
        const float* src = x + (size_t)(row0+ar)*DD + k0 + akq;
        a0 = *(const float4*)src; a1 = *(const float4*)(src+4);
        #pragma unroll
        for (int s = 0; s < 4; ++s) {
            int kb = (ks + 4*s)*2;
            const float* bp = W + (size_t)(k0 + kb)*DD + col0 + bj0;
            b0[s] = *(const float2*)bp;
            b1[s] = *(const float2*)(bp + DD);
        }
    };
    auto storeT = [&](int buf) {
        unsigned* da = (unsigned*)&As[buf][ar][akq];
        da[0] = pack2(a0.x, a0.y); da[1] = pack2(a0.z, a0.w);
        da[2] = pack2(a1.x, a1.y); da[3] = pack2(a1.z, a1.w);
        #pragma unroll
        for (int s = 0; s < 4; ++s) {
            int kb = (ks + 4*s)*2;
            *(unsigned*)&Bs[buf][bj0  ][kb] = pack2(b0[s].x, b1[s].x);
            *(unsigned*)&Bs[buf][bj0+1][kb] = pack2(b0[s].y, b1[s].y);
        }
    };

    f32x4 acc[2][4] = {};
    loadT(0); storeT(0);
    __syncthreads();
    for (int t = 0; t < 32; ++t) {
        int cur = t & 1;
        if (t < 31) loadT((t+1)*32);
        bf16x8 af[2], bfr[4];
        #pragma unroll
        for (int mf = 0; mf < 2; ++mf) af[mf] = *(const bf16x8*)&As[cur][wm*32 + mf*16 + l16][g*8];
        #pragma unroll
        for (int nf = 0; nf < 4; ++nf) bfr[nf] = *(const bf16x8*)&Bs[cur][wn*64 + nf*16 + l16][g*8];
        #pragma unroll
        for (int mf = 0; mf < 2; ++mf)
            #pragma unroll
            for (int nf = 0; nf < 4; ++nf)
                acc[mf][nf] = __builtin_amdgcn_mfma_f32_16x16x32_bf16(af[mf], bfr[nf], acc[mf][nf], 0, 0, 0);
        if (t < 31) storeT(cur ^ 1);
        __syncthreads();
    }
    #pragma unroll
    for (int mf = 0; mf < 2; ++mf)
        #pragma unroll
        for (int nf = 0; nf < 4; ++nf) {
            int cc = col0 + wn*64 + nf*16 + l16;
            float bv = bb[cc];
            #pragma unroll
            for (int r = 0; r < 4; ++r) {
                int rr = row0 + wm*32 + mf*16 + g*4 + r;
                C[(size_t)rr*DD + cc] = acc[mf][nf][r] + bv;
            }
        }
}

// ---------------------------------------------------------------------------
// bow GEMM: deltaB(bf16)[192,1024] @ bowW[1024,54945]. 512 thr, 8 waves,
// BM=192 BN=128, 2-deep register prefetch pipeline.
struct BowRegs { int4 aA, aB; float2 q00, q01, q10, q11; };

__global__ __launch_bounds__(512) void mm_bow(
        const unsigned short* __restrict__ Ab, const float* __restrict__ Bm,
        float* __restrict__ C)
{
    __shared__ __align__(16) unsigned short As[2][192][40];
    __shared__ __align__(16) unsigned short Bs[2][128][40];
    const int N = NVOCAB;
    int tid = threadIdx.x;
    int wave = tid >> 6, lane = tid & 63;
    int l16 = lane & 15, g = lane >> 4;
    int wm = wave & 3, wn = wave >> 2;
    int col0 = blockIdx.x * 128;

    int ar0 = tid >> 2, ak0 = (tid & 3) * 8;
    int ar1 = (tid + 512) >> 2;
    bool hasA1 = (tid < 256);
    int bj0 = (tid & 63) * 2, bk0 = (tid >> 6) * 2;
    int cc0 = col0 + bj0;

    auto loadT = [&](BowRegs& R, int k0) {
        R.aA = *(const int4*)(Ab + (size_t)ar0*DD + k0 + ak0);
        if (hasA1) R.aB = *(const int4*)(Ab + (size_t)ar1*DD + k0 + ak0);
        const float* bs0 = Bm + (size_t)(k0 + bk0)*N + cc0;
        const float* bs1 = bs0 + (size_t)16*N;
        if (cc0 + 1 < N) {
            R.q00 = *(const float2*)bs0;  R.q01 = *(const float2*)(bs0 + N);
            R.q10 = *(const float2*)bs1;  R.q11 = *(const float2*)(bs1 + N);
        } else if (cc0 < N) {
            R.q00 = make_float2(bs0[0], 0.f); R.q01 = make_float2(bs0[N], 0.f);
            R.q10 = make_float2(bs1[0], 0.f); R.q11 = make_float2(bs1[N], 0.f);
        } else {
            R.q00 = make_float2(0.f,0.f); R.q01 = R.q00; R.q10 = R.q00; R.q11 = R.q00;
        }
    };
    auto storeT = [&](int buf, BowRegs& R) {
        *(int4*)&As[buf][ar0][ak0] = R.aA;
        if (hasA1) *(int4*)&As[buf][ar1][ak0] = R.aB;
        *(unsigned*)&Bs[buf][bj0  ][bk0]    = pack2(R.q00.x, R.q01.x);
        *(unsigned*)&Bs[buf][bj0+1][bk0]    = pack2(R.q00.y, R.q01.y);
        *(unsigned*)&Bs[buf][bj0  ][bk0+16] = pack2(R.q10.x, R.q11.x);
        *(unsigned*)&Bs[buf][bj0+1][bk0+16] = pack2(R.q10.y, R.q11.y);
    };

    f32x4 acc[3][4] = {};
    auto compute = [&](int buf) {
        bf16x8 af[3], bfr[4];
        #pragma unroll
        for (int mf = 0; mf < 3; ++mf) af[mf] = *(const bf16x8*)&As[buf][wm*48 + mf*16 + l16][g*8];
        #pragma unroll
        for (int nf = 0; nf < 4; ++nf) bfr[nf] = *(const bf16x8*)&Bs[buf][wn*64 + nf*16 + l16][g*8];
        #pragma unroll
        for (int mf = 0; mf < 3; ++mf)
            #pragma unroll
            for (int nf = 0; nf < 4; ++nf)
                acc[mf][nf] = __builtin_amdgcn_mfma_f32_16x16x32_bf16(af[mf], bfr[nf], acc[mf][nf], 0, 0, 0);
    };

    BowRegs r0, r1;
    loadT(r0, 0); storeT(0, r0);
    loadT(r1, 32);
    __syncthreads();
    for (int t = 0; t < 32; t += 2) {
        // even iter: tile t in buf0
        if (t + 2 < 32) loadT(r0, (t+2)*32);
        compute(0);
        if (t + 1 < 32) storeT(1, r1);
        __syncthreads();
        // odd iter: tile t+1 in buf1
        if (t + 3 < 32) loadT(r1, (t+3)*32);
        compute(1);
        if (t + 2 < 32) storeT(0, r0);
        __syncthreads();
    }
    #pragma unroll
    for (int mf = 0; mf < 3; ++mf)
        #pragma unroll
        for (int nf = 0; nf < 4; ++nf) {
            int cc = col0 + wn*64 + nf*16 + l16;
            if (cc < N) {
                #pragma unroll
                for (int r = 0; r < 4; ++r) {
                    int rr = wm*48 + mf*16 + g*4 + r;
                    C[(size_t)rr*N + cc] = acc[mf][nf][r];
                }
            }
        }
}

// ---------------------------------------------------------------------------
// Prefix counts of edge types along i, LDS-staged: cnt[b,i,k] = uint2 of 8 u8
__global__ __launch_bounds__(256) void k_cnt(const int* __restrict__ et, uint2* __restrict__ cnt)
{
    __shared__ unsigned char e_sh[TT*TT];
    int b = blockIdx.x, tid = threadIdx.x;
    for (int idx = tid; idx < (TT*TT)/4; idx += 256) {
        int4 v = ((const int4*)(et + (size_t)b*TT*TT))[idx];
        unsigned pk = (unsigned)v.x | ((unsigned)v.y << 8) | ((unsigned)v.z << 16) | ((unsigned)v.w << 24);
        *(unsigned*)&e_sh[idx*4] = pk;
    }
    __syncthreads();
    int k = tid;
    if (k < TT) {
        unsigned lo = 0, hi = 0;
        for (int i = 0; i < TT; ++i) {
            int r = e_sh[i*TT + k];
            if (r < 4) lo += 1u << (8*r); else hi += 1u << (8*(r-4));
            cnt[((size_t)b*TT + i)*TT + k] = make_uint2(lo, hi);
        }
    }
}

// ---------------------------------------------------------------------------
// Fully fused attention per (b,h,half): prep (A=Q+S_diag, AR) + scores +
// softmax + PV. Grid B*H*2 = 256 blocks, 512 thr (8 waves), 36 rows/block.
__global__ __launch_bounds__(512) void k_attn(const float* __restrict__ Qb,
        const float* __restrict__ Kg, const float* __restrict__ Vg,
        const uint2* __restrict__ cnt, const float* __restrict__ rel,
        const int* __restrict__ mask, float* __restrict__ out)
{
    int bid = blockIdx.x;
    int is = bid & 1;
    int h  = (bid >> 1) & (HH-1);
    int b  = bid >> 5;
    __shared__ float K_sh[DH][TT+1];    // transposed [d][t]
    __shared__ float V_sh[TT][DH+4];    // row-major, pad 4 (16B-aligned rows)
    __shared__ float rel_sh[8][DH];
    __shared__ float a_row[8][DH];
    __shared__ float p_row[8][TT];
    int tid = threadIdx.x;
    int lane = tid & 63, w = tid >> 6;

    // stage K (transposed), V, rel
    for (int idx = tid; idx < TT*16; idx += 512) {
        int r = idx >> 4, q4 = (idx & 15) * 4;
        size_t goff = ((size_t)(b*TT + r))*DD + h*DH + q4;
        float4 kv = *(const float4*)&Kg[goff];
        K_sh[q4  ][r] = kv.x; K_sh[q4+1][r] = kv.y;
        K_sh[q4+2][r] = kv.z; K_sh[q4+3][r] = kv.w;
        float4 vv = *(const float4*)&Vg[goff];
        *(float4*)&V_sh[r][q4] = vv;
    }
    if (tid < 128) {
        int r = tid >> 4, q4 = (tid & 15) * 4;
        *(float4*)&rel_sh[r][q4] = *(const float4*)&rel[r*DD + h*DH + q4];
    }
    __syncthreads();

    for (int ii = w; ii < TT/2; ii += 8) {
        int i = is*(TT/2) + ii;
        size_t rowoff = (size_t)(b*TT + i);
        // --- prep: a = q + sum_r cr[r]*rel_r ; AR[r] = <a, rel_r>
        float q = Qb[rowoff*DD + h*DH + lane];
        float crd[8]; dec8(cnt[rowoff*TT + i], crd);
        float a = q;
        #pragma unroll
        for (int r = 0; r < 8; ++r) a += crd[r]*rel_sh[r][lane];
        a_row[w][lane] = a;
        float arr[8];
        #pragma unroll
        for (int r = 0; r < 8; ++r) {
            float pr = a * rel_sh[r][lane];
            #pragma unroll
            for (int off = 32; off; off >>= 1) pr += __shfl_xor(pr, off);
            arr[r] = pr;
        }
        // --- scores: pass1 key t=lane, pass2 key t=64+lane (lane<8)
        float s1;
        {
            int t = lane;
            float s = 0.0f;
            #pragma unroll
            for (int d0 = 0; d0 < DH; d0 += 4) {
                float4 av = *(const float4*)&a_row[w][d0];
                s += av.x*K_sh[d0][t] + av.y*K_sh[d0+1][t]
                   + av.z*K_sh[d0+2][t] + av.w*K_sh[d0+3][t];
            }
            float cr2[8]; dec8(cnt[rowoff*TT + t], cr2);
            float s2v = cr2[0]*arr[0] + cr2[1]*arr[1] + cr2[2]*arr[2] + cr2[3]*arr[3]
                      + cr2[4]*arr[4] + cr2[5]*arr[5] + cr2[6]*arr[6] + cr2[7]*arr[7];
            int m = mask[rowoff*TT + t];
            s1 = (m == 0) ? -1e9f : (s + s2v)*0.125f;
        }
        float s2 = -1e30f;
        if (lane < TT - DH) {
            int t = DH + lane;
            float s = 0.0f;
            #pragma unroll
            for (int d0 = 0; d0 < DH; d0 += 4) {
                float4 av = *(const float4*)&a_row[w][d0];
                s += av.x*K_sh[d0][t] + av.y*K_sh[d0+1][t]
                   + av.z*K_sh[d0+2][t] + av.w*K_sh[d0+3][t];
            }
            float cr2[8]; dec8(cnt[rowoff*TT + t], cr2);
            float s2v = cr2[0]*arr[0] + cr2[1]*arr[1] + cr2[2]*arr[2] + cr2[3]*arr[3]
                      + cr2[4]*arr[4] + cr2[5]*arr[5] + cr2[6]*arr[6] + cr2[7]*arr[7];
            int m = mask[rowoff*TT + t];
            s2 = (m == 0) ? -1e9f : (s + s2v)*0.125f;
        }
        // --- softmax over 72
        float mx = fmaxf(s1, s2);
        #pragma unroll
        for (int off = 32; off; off >>= 1) mx = fmaxf(mx, __shfl_xor(mx, off));
        float e1 = __expf(s1 - mx);
        float e2 = (lane < TT - DH) ? __expf(s2 - mx) : 0.0f;
        float sm = e1 + e2;
        #pragma unroll
        for (int off = 32; off; off >>= 1) sm += __shfl_xor(sm, off);
        float inv = 1.0f / sm;
        p_row[w][lane] = e1 * inv;
        if (lane < TT - DH) p_row[w][DH + lane] = e2 * inv;
        // --- PV: lane owns d = lane
        float o = 0.0f;
        #pragma unroll 8
        for (int t = 0; t < TT; ++t) o += p_row[w][t] * V_sh[t][lane];
        out[rowoff*DD + h*DH + lane] = o;
    }
}

// ---------------------------------------------------------------------------
// Merged epilogue: output splits + delta(bf16) + strategy/emotion logits
__global__ __launch_bounds__(256) void k_finlog(const float* __restrict__ outs,
        const float* __restrict__ sem_cls,
        const float* __restrict__ strW, const float* __restrict__ strB,
        const float* __restrict__ emoW, const float* __restrict__ emoB,
        float* __restrict__ o_last_stra, float* __restrict__ o_emo,
        float* __restrict__ o_last_delta, float* __restrict__ o_str,
        float* __restrict__ o_emo_log, unsigned short* __restrict__ deltaB)
{
    __shared__ float part[14][16];
    int bid = blockIdx.x; int b = bid / UU, u = bid % UU;
    const float* sem = outs + ((size_t)(b*TT + 3*u))*DD;
    const float* st  = sem + DD;
    const float* em  = st + DD;
    const float* sc  = sem_cls + ((size_t)(b*UU + u))*DD;
    unsigned short* de = deltaB + ((size_t)(b*UU + u))*DD;
    float* oe = o_emo + ((size_t)(b*UU + u))*DD;
    int t = threadIdx.x;
    for (int d = t; d < DD; d += 256) {
        float dl = sem[d] - sc[d];
        de[d] = f2b(dl); oe[d] = em[d];
        if (u == UU-1) { o_last_stra[b*DD + d] = st[d]; o_last_delta[b*DD + d] = dl; }
    }
    if (t < 224) {
        int o = t >> 4, c = t & 15;
        float s = 0.0f;
        if (o < 8) {
            for (int d = c*64; d < c*64 + 64; ++d) s += st[d]*strW[d*8 + o];
        } else {
            int j = o - 8;
            for (int d = c*64; d < c*64 + 64; ++d) s += em[d]*emoW[d*6 + j];
        }
        part[o][c] = s;
    }
    __syncthreads();
    if (t < 14) {
        float s = 0.0f;
        #pragma unroll
        for (int c2 = 0; c2 < 16; ++c2) s += part[t][c2];
        if (t < 8) o_str[(b*UU + u)*8 + t] = s + strB[t];
        else       o_emo_log[(b*UU + u)*6 + (t-8)] = s + emoB[t-8];
    }
}

// ---------------------------------------------------------------------------
extern "C" void kernel_launch(void* const* d_in, const int* in_sizes, int n_in,
                              void* d_out, int out_size, void* d_ws, size_t ws_size,
                              hipStream_t stream)
{
    const float* hidden  = (const float*)d_in[0];
    const float* emo_csk = (const float*)d_in[1];
    const float* Wq  = (const float*)d_in[2];
    const float* bq  = (const float*)d_in[3];
    const float* Wk  = (const float*)d_in[4];
    const float* bk  = (const float*)d_in[5];
    const float* Wv  = (const float*)d_in[6];
    const float* bv  = (const float*)d_in[7];
    const float* rel = (const float*)d_in[8];
    const float* fusW = (const float*)d_in[9];
    const float* fusB = (const float*)d_in[10];
    const float* bng = (const float*)d_in[11];
    const float* bnb = (const float*)d_in[12];
    const float* bnm = (const float*)d_in[13];
    const float* bnv = (const float*)d_in[14];
    const float* cskW = (const float*)d_in[15];
    const float* cskB = (const float*)d_in[16];
    const float* emoW = (const float*)d_in[17];
    const float* emoB = (const float*)d_in[18];
    const float* strW = (const float*)d_in[19];
    const float* strB = (const float*)d_in[20];
    const float* bowW = (const float*)d_in[21];
    const int* clsIdx = (const int*)d_in[22];
    const int* tGraph = (const int*)d_in[23];
    const int* iGraph = (const int*)d_in[24];
    const int* tEdge  = (const int*)d_in[25];
    const int* iEdge  = (const int*)d_in[26];

    float* out = (float*)d_out;
    float* o_last_stra  = out;             // B*D          = 8192
    float* o_emo_trans  = out + 8192;      // B*U*D        = 196608
    float* o_last_delta = out + 204800;    // B*D          = 8192
    float* o_sem_cls    = out + 212992;    // B*U*D        = 196608
    float* o_str_log    = out + 409600;    // B*U*8        = 1536
    float* o_emo_log    = out + 411136;    // B*U*6        = 1152
    float* o_bow        = out + 412288;    // B*U*VOCAB

    float* ws = (float*)d_ws;
    const int SZ_BTD = BB*TT*DD;   // 589824
    const int SZ_BUD = BB*UU*DD;   // 196608
    float* trans_in  = ws;
    float* Qb        = trans_in + SZ_BTD;
    float* Kb        = Qb + SZ_BTD;
    float* Vb        = Kb + SZ_BTD;
    float* trans_out = Vb + SZ_BTD;
    float* inter_out = trans_out + SZ_BTD;
    float* outsB     = inter_out + SZ_BTD;
    float* csk_norm  = outsB + SZ_BTD;
    float* cnt_f     = csk_norm + SZ_BUD;
    uint2* cntb      = (uint2*)cnt_f;                  // B*T*T uint2
    unsigned short* deltaB = (unsigned short*)(cnt_f + BB*TT*TT*2);

    // 1. gather cls + build trans_in; write sem_cls_embs
    k_gather_cls<<<dim3(BB*UU), dim3(256), 0, stream>>>(hidden, clsIdx, o_sem_cls, trans_in);
    // 2. batchnorm
    int nbn = BB*UU*CSKN;
    k_bn<<<dim3((nbn+255)/256), dim3(256), 0, stream>>>(emo_csk, bng, bnb, bnm, bnv, csk_norm, nbn);
    // 3. csk_proj GEMM fused with scatter-add into trans_in[:,2::3]
    mm64<4><<<dim3(16, 3), dim3(256), 0, stream>>>(csk_norm, nullptr, CSKN, cskW, cskB,
            nullptr, nullptr, trans_in, DD, CSKN);

    auto attention = [&](const float* x, const int* graph, const int* edge, float* ctx_out) {
        mm_qkv<<<dim3(24, (BB*TT)/64), dim3(256), 0, stream>>>(x, Wq, Wk, Wv, bq, bk, bv, Qb, Kb, Vb);
        k_cnt<<<dim3(BB), dim3(256), 0, stream>>>(edge, cntb);
        k_attn<<<dim3(BB*HH*2), dim3(512), 0, stream>>>(Qb, Kb, Vb, cntb, rel, graph, ctx_out);
    };
    attention(trans_in, tGraph, tEdge, trans_out);
    attention(trans_out, iGraph, iEdge, inter_out);

    // fusion gate + blend fused: outsB = g*trans + (1-g)*inter
    mm64<3><<<dim3(16, (BB*TT)/64), dim3(256), 0, stream>>>(trans_out, inter_out, DD, fusW, fusB,
            trans_out, inter_out, outsB, DD, 2*DD);

    // merged epilogue (writes deltaB bf16 + small logits)
    k_finlog<<<dim3(BB*UU), dim3(256), 0, stream>>>(outsB, o_sem_cls, strW, strB, emoW, emoB,
            o_last_stra, o_emo_trans, o_last_delta, o_str_log, o_emo_log, deltaB);

    // bow_logits = delta @ bow_W
    mm_bow<<<dim3((NVOCAB+127)/128), dim3(512), 0, stream>>>(deltaB, bowW, o_bow);
}

// Round 6
// 327.788 us; speedup vs baseline: 1.0994x; 1.0994x over previous
//
#include <hip/hip_runtime.h>
#include <math.h>

// Problem constants
#define BB 8
#define LL 512
#define UU 24
#define DD 1024
#define HH 16
#define DH 64
#define TT 72
#define CSKN 1024
#define NVOCAB 54945

typedef __attribute__((ext_vector_type(8))) short bf16x8;
typedef __attribute__((ext_vector_type(4))) float f32x4;

__device__ inline unsigned short f2b(float x) {
    unsigned u = __float_as_uint(x);
    unsigned r = u + 0x7FFFu + ((u >> 16) & 1u);
    return (unsigned short)(r >> 16);
}
__device__ inline unsigned pack2(float lo, float hi) {
    return (unsigned)f2b(lo) | ((unsigned)f2b(hi) << 16);
}
__device__ inline void dec8(uint2 c, float* cr) {
    cr[0] = (float)( c.x        & 0xff); cr[1] = (float)((c.x >>  8) & 0xff);
    cr[2] = (float)((c.x >> 16) & 0xff); cr[3] = (float)((c.x >> 24) & 0xff);
    cr[4] = (float)( c.y        & 0xff); cr[5] = (float)((c.y >>  8) & 0xff);
    cr[6] = (float)((c.y >> 16) & 0xff); cr[7] = (float)((c.y >> 24) & 0xff);
}

// ---------------------------------------------------------------------------
__global__ __launch_bounds__(256) void k_gather_cls(const float* __restrict__ hidden,
        const int* __restrict__ idx, float* __restrict__ sem_cls, float* __restrict__ trans_in)
{
    int bid = blockIdx.x; int b = bid / UU, u = bid % UU;
    int row = idx[b*UU + u];
    const float* src = hidden + ((size_t)(b*LL + row))*DD;
    float* d0 = trans_in + ((size_t)(b*TT + 3*u))*DD;
    float* sc = sem_cls + ((size_t)(b*UU + u))*DD;
    for (int d = threadIdx.x; d < DD; d += 256) {
        float v = src[d];
        sc[d] = v;
        d0[d] = v; d0[DD + d] = v; d0[2*DD + d] = v;
    }
}

__global__ void k_bn(const float* __restrict__ x, const float* __restrict__ g,
                     const float* __restrict__ be, const float* __restrict__ mu,
                     const float* __restrict__ var, float* __restrict__ y, int n)
{
    int i = blockIdx.x*256 + threadIdx.x;
    if (i >= n) return;
    int c = i % CSKN;
    y[i] = (x[i] - mu[c]) * (1.0f/sqrtf(var[c] + 1e-5f)) * g[c] + be[c];
}

// ---------------------------------------------------------------------------
// Double-buffered MFMA bf16 GEMM, 64x64 tile, 256 thr, 4 waves (2x2).
// EPI: 3 = gate-blend C=g*ep1+(1-g)*ep2, g=sigmoid(A@B+bias)
//      4 = csk: trans_in[b*72+3u+2][cc] += (A@B+bias), skip u==U-1 (C=trans_in)
template<int EPI>
__global__ __launch_bounds__(256) void mm64(
        const float* __restrict__ A1, const float* __restrict__ A2, int K1,
        const float* __restrict__ Bm, const float* __restrict__ bias,
        const float* __restrict__ ep1, const float* __restrict__ ep2,
        float* __restrict__ C, int N, int K)
{
    __shared__ __align__(16) unsigned short As[2][64][40];
    __shared__ __align__(16) unsigned short Bs[2][64][40];
    int tid = threadIdx.x;
    int wave = tid >> 6, lane = tid & 63;
    int l16 = lane & 15, g = lane >> 4;
    int wm = wave & 1, wn = wave >> 1;
    int row0 = blockIdx.y * 64, col0 = blockIdx.x * 64;

    int ar = tid >> 2, akq = (tid & 3) * 8;
    int bj0 = (tid & 31) * 2, bk0 = (tid >> 5) * 2;
    float4 a0, a1;
    float2 q00, q01, q10, q11;

    auto loadT = [&](int k0) {
        int kk = k0 + akq;
        const float* src = (kk < K1) ? A1 + (size_t)(row0+ar)*K1 + kk
                                     : A2 + (size_t)(row0+ar)*(K-K1) + (kk-K1);
        a0 = *(const float4*)src; a1 = *(const float4*)(src+4);
        const float* bs0 = Bm + (size_t)(k0 + bk0)*N + col0 + bj0;
        q00 = *(const float2*)bs0;       q01 = *(const float2*)(bs0 + N);
        const float* bs1 = bs0 + (size_t)16*N;
        q10 = *(const float2*)bs1;       q11 = *(const float2*)(bs1 + N);
    };
    auto storeT = [&](int buf) {
        unsigned* da = (unsigned*)&As[buf][ar][akq];
        da[0] = pack2(a0.x, a0.y); da[1] = pack2(a0.z, a0.w);
        da[2] = pack2(a1.x, a1.y); da[3] = pack2(a1.z, a1.w);
        *(unsigned*)&Bs[buf][bj0  ][bk0]    = pack2(q00.x, q01.x);
        *(unsigned*)&Bs[buf][bj0+1][bk0]    = pack2(q00.y, q01.y);
        *(unsigned*)&Bs[buf][bj0  ][bk0+16] = pack2(q10.x, q11.x);
        *(unsigned*)&Bs[buf][bj0+1][bk0+16] = pack2(q10.y, q11.y);
    };

    f32x4 acc[2][2] = {};
    loadT(0); storeT(0);
    __syncthreads();
    int nt = K / 32;
    for (int t = 0; t < nt; ++t) {
        int cur = t & 1;
        if (t + 1 < nt) loadT((t+1)*32);
        bf16x8 af[2], bfr[2];
        #pragma unroll
        for (int mf = 0; mf < 2; ++mf) af[mf] = *(const bf16x8*)&As[cur][wm*32 + mf*16 + l16][g*8];
        #pragma unroll
        for (int nf = 0; nf < 2; ++nf) bfr[nf] = *(const bf16x8*)&Bs[cur][wn*32 + nf*16 + l16][g*8];
        #pragma unroll
        for (int mf = 0; mf < 2; ++mf)
            #pragma unroll
            for (int nf = 0; nf < 2; ++nf)
                acc[mf][nf] = __builtin_amdgcn_mfma_f32_16x16x32_bf16(af[mf], bfr[nf], acc[mf][nf], 0, 0, 0);
        if (t + 1 < nt) storeT(cur ^ 1);
        __syncthreads();
    }
    #pragma unroll
    for (int mf = 0; mf < 2; ++mf)
        #pragma unroll
        for (int nf = 0; nf < 2; ++nf) {
            int cc = col0 + wn*32 + nf*16 + l16;
            float bv = bias[cc];
            #pragma unroll
            for (int r = 0; r < 4; ++r) {
                int rr = row0 + wm*32 + mf*16 + g*4 + r;
                float v = acc[mf][nf][r] + bv;
                if (EPI == 3) {
                    float gg = 1.0f/(1.0f + __expf(-v));
                    float tv = ep1[(size_t)rr*N + cc];
                    float iv = ep2[(size_t)rr*N + cc];
                    C[(size_t)rr*N + cc] = gg*tv + (1.0f - gg)*iv;
                } else { // EPI == 4
                    int bq = rr / UU, uq = rr % UU;
                    if (uq < UU-1) {
                        float* dst = &C[((size_t)(bq*TT + 3*uq + 2))*DD + cc];
                        *dst += v;
                    }
                }
            }
        }
}

// ---------------------------------------------------------------------------
// Fused Q/K/V projection, BM=64 BN=128, dbuf. Grid (24, 9); blockIdx.x>>3 selects.
__global__ __launch_bounds__(256) void mm_qkv(
        const float* __restrict__ x,
        const float* __restrict__ W0, const float* __restrict__ W1, const float* __restrict__ W2,
        const float* __restrict__ v0, const float* __restrict__ v1, const float* __restrict__ v2,
        float* __restrict__ C0, float* __restrict__ C1, float* __restrict__ C2)
{
    __shared__ __align__(16) unsigned short As[2][64][40];
    __shared__ __align__(16) unsigned short Bs[2][128][40];
    int which = blockIdx.x >> 3;
    int col0 = (blockIdx.x & 7) * 128;
    int row0 = blockIdx.y * 64;
    const float* W  = (which == 0) ? W0 : (which == 1) ? W1 : W2;
    const float* bb = (which == 0) ? v0 : (which == 1) ? v1 : v2;
    float*       C  = (which == 0) ? C0 : (which == 1) ? C1 : C2;
    int tid = threadIdx.x;
    int wave = tid >> 6, lane = tid & 63;
    int l16 = lane & 15, g = lane >> 4;
    int wm = wave & 1, wn = wave >> 1;

    int ar = tid >> 2, akq = (tid & 3) * 8;
    int bj0 = (tid & 63) * 2, ks = tid >> 6;   // 4 k-pair slots per thread
    float4 a0, a1;
    float2 b0[4], b1[4];

    auto loadT = [&](int k0) {
        const float* src = x + (size_t)(row0+ar)*DD + k0 + akq;
        a0 = *(const float4*)src; a1 = *(const float4*)(src+4);
        #pragma unroll
        for (int s = 0; s < 4; ++s) {
            int kb = (ks + 4*s)*2;
            const float* bp = W + (size_t)(k0 + kb)*DD + col0 + bj0;
            b0[s] = *(const float2*)bp;
            b1[s] = *(const float2*)(bp + DD);
        }
    };
    auto storeT = [&](int buf) {
        unsigned* da = (unsigned*)&As[buf][ar][akq];
        da[0] = pack2(a0.x, a0.y); da[1] = pack2(a0.z, a0.w);
        da[2] = pack2(a1.x, a1.y); da[3] = pack2(a1.z, a1.w);
        #pragma unroll
        for (int s = 0; s < 4; ++s) {
            int kb = (ks + 4*s)*2;
            *(unsigned*)&Bs[buf][bj0  ][kb] = pack2(b0[s].x, b1[s].x);
            *(unsigned*)&Bs[buf][bj0+1][kb] = pack2(b0[s].y, b1[s].y);
        }
    };

    f32x4 acc[2][4] = {};
    loadT(0); storeT(0);
    __syncthreads();
    for (int t = 0; t < 32; ++t) {
        int cur = t & 1;
        if (t < 31) loadT((t+1)*32);
        bf16x8 af[2], bfr[4];
        #pragma unroll
        for (int mf = 0; mf < 2; ++mf) af[mf] = *(const bf16x8*)&As[cur][wm*32 + mf*16 + l16][g*8];
        #pragma unroll
        for (int nf = 0; nf < 4; ++nf) bfr[nf] = *(const bf16x8*)&Bs[cur][wn*64 + nf*16 + l16][g*8];
        #pragma unroll
        for (int mf = 0; mf < 2; ++mf)
            #pragma unroll
            for (int nf = 0; nf < 4; ++nf)
                acc[mf][nf] = __builtin_amdgcn_mfma_f32_16x16x32_bf16(af[mf], bfr[nf], acc[mf][nf], 0, 0, 0);
        if (t < 31) storeT(cur ^ 1);
        __syncthreads();
    }
    #pragma unroll
    for (int mf = 0; mf < 2; ++mf)
        #pragma unroll
        for (int nf = 0; nf < 4; ++nf) {
            int cc = col0 + wn*64 + nf*16 + l16;
            float bv = bb[cc];
            #pragma unroll
            for (int r = 0; r < 4; ++r) {
                int rr = row0 + wm*32 + mf*16 + g*4 + r;
                C[(size_t)rr*DD + cc] = acc[mf][nf][r] + bv;
            }
        }
}

// ---------------------------------------------------------------------------
// bow GEMM: deltaB(bf16)[192,1024] @ bowW[1024,54945] -> o_bow.
// 256 thr / 4 waves; wave owns 16 cols; B-fragments loaded DIRECTLY from
// global (16-lane 64B segments = full line utilization), 2-deep reg prefetch.
// Only A (12KB/k-iter slice) goes through LDS, double-buffered, reg-staged.
__global__ __launch_bounds__(256) void mm_bow(
        const unsigned short* __restrict__ Ab, const float* __restrict__ Bm,
        float* __restrict__ C)
{
    __shared__ __align__(16) unsigned short A_lds[2][192][40];
    const int N = NVOCAB;
    int tid = threadIdx.x;
    int lane = tid & 63, wave = tid >> 6;
    int l16 = lane & 15, g = lane >> 4;
    int col = blockIdx.x * 64 + wave * 16 + l16;
    int colc = (col < N) ? col : (N - 1);
    const float* bbase = Bm + (size_t)(g * 8) * N + colc;

    int r0 = tid >> 2,          q0 = (tid & 3) * 8;
    int r1 = (tid + 256) >> 2,  q1 = ((tid + 256) & 3) * 8;
    int r2 = (tid + 512) >> 2,  q2 = ((tid + 512) & 3) * 8;
    int4 ra0, ra1, ra2;
    auto loadA = [&](int k0) {
        ra0 = *(const int4*)(Ab + (size_t)r0 * DD + k0 + q0);
        ra1 = *(const int4*)(Ab + (size_t)r1 * DD + k0 + q1);
        ra2 = *(const int4*)(Ab + (size_t)r2 * DD + k0 + q2);
    };
    auto writeA = [&](int buf) {
        *(int4*)&A_lds[buf][r0][q0] = ra0;
        *(int4*)&A_lds[buf][r1][q1] = ra1;
        *(int4*)&A_lds[buf][r2][q2] = ra2;
    };

    f32x4 acc[12] = {};
    float bA[8], bB[8];

#define LOADB(dst, t_) { const float* bp = bbase + (size_t)(t_) * 32 * N;      \
        _Pragma("unroll") for (int j = 0; j < 8; ++j) dst[j] = bp[(size_t)j * N]; }
#define PACKB(fr, sv) { _Pragma("unroll") for (int j = 0; j < 8; ++j)          \
        ((unsigned short*)&fr)[j] = f2b(sv[j]); }
#define MFMA12(buf, fr) { _Pragma("unroll") for (int mf = 0; mf < 12; ++mf) {  \
        bf16x8 af = *(const bf16x8*)&A_lds[buf][mf * 16 + l16][g * 8];         \
        acc[mf] = __builtin_amdgcn_mfma_f32_16x16x32_bf16(af, fr, acc[mf], 0, 0, 0); } }

    LOADB(bA, 0); LOADB(bB, 1);
    loadA(0); writeA(0);
    loadA(32);
    __syncthreads();
    for (int t = 0; t < 32; t += 2) {
        bf16x8 fr;
        PACKB(fr, bA);
        if (t + 2 < 32) LOADB(bA, t + 2);
        MFMA12(0, fr);
        if (t + 1 < 32) writeA(1);
        if (t + 2 < 32) loadA((t + 2) * 32);
        __syncthreads();
        PACKB(fr, bB);
        if (t + 3 < 32) LOADB(bB, t + 3);
        MFMA12(1, fr);
        if (t + 2 < 32) writeA(0);
        if (t + 3 < 32) loadA((t + 3) * 32);
        __syncthreads();
    }
#undef LOADB
#undef PACKB
#undef MFMA12
    if (col < N) {
        #pragma unroll
        for (int mf = 0; mf < 12; ++mf)
            #pragma unroll
            for (int r = 0; r < 4; ++r)
                C[(size_t)(mf * 16 + g * 4 + r) * N + col] = acc[mf][r];
    }
}

// ---------------------------------------------------------------------------
// Prefix counts of edge types along i, LDS-staged: cnt[b,i,k] = uint2 of 8 u8
__global__ __launch_bounds__(256) void k_cnt(const int* __restrict__ et, uint2* __restrict__ cnt)
{
    __shared__ unsigned char e_sh[TT*TT];
    int b = blockIdx.x, tid = threadIdx.x;
    for (int idx = tid; idx < (TT*TT)/4; idx += 256) {
        int4 v = ((const int4*)(et + (size_t)b*TT*TT))[idx];
        unsigned pk = (unsigned)v.x | ((unsigned)v.y << 8) | ((unsigned)v.z << 16) | ((unsigned)v.w << 24);
        *(unsigned*)&e_sh[idx*4] = pk;
    }
    __syncthreads();
    int k = tid;
    if (k < TT) {
        unsigned lo = 0, hi = 0;
        for (int i = 0; i < TT; ++i) {
            int r = e_sh[i*TT + k];
            if (r < 4) lo += 1u << (8*r); else hi += 1u << (8*(r-4));
            cnt[((size_t)b*TT + i)*TT + k] = make_uint2(lo, hi);
        }
    }
}

// ---------------------------------------------------------------------------
// Fully fused attention per (b,h,half): prep (A=Q+S_diag, AR) + scores +
// softmax + PV. Grid B*H*2 = 256 blocks, 512 thr (8 waves), 36 rows/block.
__global__ __launch_bounds__(512) void k_attn(const float* __restrict__ Qb,
        const float* __restrict__ Kg, const float* __restrict__ Vg,
        const uint2* __restrict__ cnt, const float* __restrict__ rel,
        const int* __restrict__ mask, float* __restrict__ out)
{
    int bid = blockIdx.x;
    int is = bid & 1;
    int h  = (bid >> 1) & (HH-1);
    int b  = bid >> 5;
    __shared__ float K_sh[DH][TT+1];    // transposed [d][t]
    __shared__ float V_sh[TT][DH+4];    // row-major, pad 4 (16B-aligned rows)
    __shared__ float rel_sh[8][DH];
    __shared__ float a_row[8][DH];
    __shared__ float p_row[8][TT];
    int tid = threadIdx.x;
    int lane = tid & 63, w = tid >> 6;

    // stage K (transposed), V, rel
    for (int idx = tid; idx < TT*16; idx += 512) {
        int r = idx >> 4, q4 = (idx & 15) * 4;
        size_t goff = ((size_t)(b*TT + r))*DD + h*DH + q4;
        float4 kv = *(const float4*)&Kg[goff];
        K_sh[q4  ][r] = kv.x; K_sh[q4+1][r] = kv.y;
        K_sh[q4+2][r] = kv.z; K_sh[q4+3][r] = kv.w;
        float4 vv = *(const float4*)&Vg[goff];
        *(float4*)&V_sh[r][q4] = vv;
    }
    if (tid < 128) {
        int r = tid >> 4, q4 = (tid & 15) * 4;
        *(float4*)&rel_sh[r][q4] = *(const float4*)&rel[r*DD + h*DH + q4];
    }
    __syncthreads();

    for (int ii = w; ii < TT/2; ii += 8) {
        int i = is*(TT/2) + ii;
        size_t rowoff = (size_t)(b*TT + i);
        // --- prep: a = q + sum_r cr[r]*rel_r ; AR[r] = <a, rel_r>
        float q = Qb[rowoff*DD + h*DH + lane];
        float crd[8]; dec8(cnt[rowoff*TT + i], crd);
        float a = q;
        #pragma unroll
        for (int r = 0; r < 8; ++r) a += crd[r]*rel_sh[r][lane];
        a_row[w][lane] = a;
        float arr[8];
        #pragma unroll
        for (int r = 0; r < 8; ++r) {
            float pr = a * rel_sh[r][lane];
            #pragma unroll
            for (int off = 32; off; off >>= 1) pr += __shfl_xor(pr, off);
            arr[r] = pr;
        }
        // --- scores: pass1 key t=lane, pass2 key t=64+lane (lane<8)
        float s1;
        {
            int t = lane;
            float s = 0.0f;
            #pragma unroll
            for (int d0 = 0; d0 < DH; d0 += 4) {
                float4 av = *(const float4*)&a_row[w][d0];
                s += av.x*K_sh[d0][t] + av.y*K_sh[d0+1][t]
                   + av.z*K_sh[d0+2][t] + av.w*K_sh[d0+3][t];
            }
            float cr2[8]; dec8(cnt[rowoff*TT + t], cr2);
            float s2v = cr2[0]*arr[0] + cr2[1]*arr[1] + cr2[2]*arr[2] + cr2[3]*arr[3]
                      + cr2[4]*arr[4] + cr2[5]*arr[5] + cr2[6]*arr[6] + cr2[7]*arr[7];
            int m = mask[rowoff*TT + t];
            s1 = (m == 0) ? -1e9f : (s + s2v)*0.125f;
        }
        float s2 = -1e30f;
        if (lane < TT - DH) {
            int t = DH + lane;
            float s = 0.0f;
            #pragma unroll
            for (int d0 = 0; d0 < DH; d0 += 4) {
                float4 av = *(const float4*)&a_row[w][d0];
                s += av.x*K_sh[d0][t] + av.y*K_sh[d0+1][t]
                   + av.z*K_sh[d0+2][t] + av.w*K_sh[d0+3][t];
            }
            float cr2[8]; dec8(cnt[rowoff*TT + t], cr2);
            float s2v = cr2[0]*arr[0] + cr2[1]*arr[1] + cr2[2]*arr[2] + cr2[3]*arr[3]
                      + cr2[4]*arr[4] + cr2[5]*arr[5] + cr2[6]*arr[6] + cr2[7]*arr[7];
            int m = mask[rowoff*TT + t];
            s2 = (m == 0) ? -1e9f : (s + s2v)*0.125f;
        }
        // --- softmax over 72
        float mx = fmaxf(s1, s2);
        #pragma unroll
        for (int off = 32; off; off >>= 1) mx = fmaxf(mx, __shfl_xor(mx, off));
        float e1 = __expf(s1 - mx);
        float e2 = (lane < TT - DH) ? __expf(s2 - mx) : 0.0f;
        float sm = e1 + e2;
        #pragma unroll
        for (int off = 32; off; off >>= 1) sm += __shfl_xor(sm, off);
        float inv = 1.0f / sm;
        p_row[w][lane] = e1 * inv;
        if (lane < TT - DH) p_row[w][DH + lane] = e2 * inv;
        // --- PV: lane owns d = lane
        float o = 0.0f;
        #pragma unroll 8
        for (int t = 0; t < TT; ++t) o += p_row[w][t] * V_sh[t][lane];
        out[rowoff*DD + h*DH + lane] = o;
    }
}

// ---------------------------------------------------------------------------
// Merged epilogue: output splits + delta(bf16) + strategy/emotion logits
__global__ __launch_bounds__(256) void k_finlog(const float* __restrict__ outs,
        const float* __restrict__ sem_cls,
        const float* __restrict__ strW, const float* __restrict__ strB,
        const float* __restrict__ emoW, const float* __restrict__ emoB,
        float* __restrict__ o_last_stra, float* __restrict__ o_emo,
        float* __restrict__ o_last_delta, float* __restrict__ o_str,
        float* __restrict__ o_emo_log, unsigned short* __restrict__ deltaB)
{
    __shared__ float part[14][16];
    int bid = blockIdx.x; int b = bid / UU, u = bid % UU;
    const float* sem = outs + ((size_t)(b*TT + 3*u))*DD;
    const float* st  = sem + DD;
    const float* em  = st + DD;
    const float* sc  = sem_cls + ((size_t)(b*UU + u))*DD;
    unsigned short* de = deltaB + ((size_t)(b*UU + u))*DD;
    float* oe = o_emo + ((size_t)(b*UU + u))*DD;
    int t = threadIdx.x;
    for (int d = t; d < DD; d += 256) {
        float dl = sem[d] - sc[d];
        de[d] = f2b(dl); oe[d] = em[d];
        if (u == UU-1) { o_last_stra[b*DD + d] = st[d]; o_last_delta[b*DD + d] = dl; }
    }
    if (t < 224) {
        int o = t >> 4, c = t & 15;
        float s = 0.0f;
        if (o < 8) {
            for (int d = c*64; d < c*64 + 64; ++d) s += st[d]*strW[d*8 + o];
        } else {
            int j = o - 8;
            for (int d = c*64; d < c*64 + 64; ++d) s += em[d]*emoW[d*6 + j];
        }
        part[o][c] = s;
    }
    __syncthreads();
    if (t < 14) {
        float s = 0.0f;
        #pragma unroll
        for (int c2 = 0; c2 < 16; ++c2) s += part[t][c2];
        if (t < 8) o_str[(b*UU + u)*8 + t] = s + strB[t];
        else       o_emo_log[(b*UU + u)*6 + (t-8)] = s + emoB[t-8];
    }
}

// ---------------------------------------------------------------------------
extern "C" void kernel_launch(void* const* d_in, const int* in_sizes, int n_in,
                              void* d_out, int out_size, void* d_ws, size_t ws_size,
                              hipStream_t stream)
{
    const float* hidden  = (const float*)d_in[0];
    const float* emo_csk = (const float*)d_in[1];
    const float* Wq  = (const float*)d_in[2];
    const float* bq  = (const float*)d_in[3];
    const float* Wk  = (const float*)d_in[4];
    const float* bk  = (const float*)d_in[5];
    const float* Wv  = (const float*)d_in[6];
    const float* bv  = (const float*)d_in[7];
    const float* rel = (const float*)d_in[8];
    const float* fusW = (const float*)d_in[9];
    const float* fusB = (const float*)d_in[10];
    const float* bng = (const float*)d_in[11];
    const float* bnb = (const float*)d_in[12];
    const float* bnm = (const float*)d_in[13];
    const float* bnv = (const float*)d_in[14];
    const float* cskW = (const float*)d_in[15];
    const float* cskB = (const float*)d_in[16];
    const float* emoW = (const float*)d_in[17];
    const float* emoB = (const float*)d_in[18];
    const float* strW = (const float*)d_in[19];
    const float* strB = (const float*)d_in[20];
    const float* bowW = (const float*)d_in[21];
    const int* clsIdx = (const int*)d_in[22];
    const int* tGraph = (const int*)d_in[23];
    const int* iGraph = (const int*)d_in[24];
    const int* tEdge  = (const int*)d_in[25];
    const int* iEdge  = (const int*)d_in[26];

    float* out = (float*)d_out;
    float* o_last_stra  = out;             // B*D          = 8192
    float* o_emo_trans  = out + 8192;      // B*U*D        = 196608
    float* o_last_delta = out + 204800;    // B*D          = 8192
    float* o_sem_cls    = out + 212992;    // B*U*D        = 196608
    float* o_str_log    = out + 409600;    // B*U*8        = 1536
    float* o_emo_log    = out + 411136;    // B*U*6        = 1152
    float* o_bow        = out + 412288;    // B*U*VOCAB

    float* ws = (float*)d_ws;
    const int SZ_BTD = BB*TT*DD;   // 589824
    const int SZ_BUD = BB*UU*DD;   // 196608
    float* trans_in  = ws;
    float* Qb        = trans_in + SZ_BTD;
    float* Kb        = Qb + SZ_BTD;
    float* Vb        = Kb + SZ_BTD;
    float* trans_out = Vb + SZ_BTD;
    float* inter_out = trans_out + SZ_BTD;
    float* outsB     = inter_out + SZ_BTD;
    float* csk_norm  = outsB + SZ_BTD;
    float* cnt_f     = csk_norm + SZ_BUD;
    uint2* cntb      = (uint2*)cnt_f;                  // B*T*T uint2
    unsigned short* deltaB = (unsigned short*)(cnt_f + BB*TT*TT*2);

    // 1. gather cls + build trans_in; write sem_cls_embs
    k_gather_cls<<<dim3(BB*UU), dim3(256), 0, stream>>>(hidden, clsIdx, o_sem_cls, trans_in);
    // 2. batchnorm
    int nbn = BB*UU*CSKN;
    k_bn<<<dim3((nbn+255)/256), dim3(256), 0, stream>>>(emo_csk, bng, bnb, bnm, bnv, csk_norm, nbn);
    // 3. csk_proj GEMM fused with scatter-add into trans_in[:,2::3]
    mm64<4><<<dim3(16, 3), dim3(256), 0, stream>>>(csk_norm, nullptr, CSKN, cskW, cskB,
            nullptr, nullptr, trans_in, DD, CSKN);

    auto attention = [&](const float* x, const int* graph, const int* edge, float* ctx_out) {
        mm_qkv<<<dim3(24, (BB*TT)/64), dim3(256), 0, stream>>>(x, Wq, Wk, Wv, bq, bk, bv, Qb, Kb, Vb);
        k_cnt<<<dim3(BB), dim3(256), 0, stream>>>(edge, cntb);
        k_attn<<<dim3(BB*HH*2), dim3(512), 0, stream>>>(Qb, Kb, Vb, cntb, rel, graph, ctx_out);
    };
    attention(trans_in, tGraph, tEdge, trans_out);
    attention(trans_out, iGraph, iEdge, inter_out);

    // fusion gate + blend fused: outsB = g*trans + (1-g)*inter
    mm64<3><<<dim3(16, (BB*TT)/64), dim3(256), 0, stream>>>(trans_out, inter_out, DD, fusW, fusB,
            trans_out, inter_out, outsB, DD, 2*DD);

    // merged epilogue (writes deltaB bf16 + small logits)
    k_finlog<<<dim3(BB*UU), dim3(256), 0, stream>>>(outsB, o_sem_cls, strW, strB, emoW, emoB,
            o_last_stra, o_emo_trans, o_last_delta, o_str_log, o_emo_log, deltaB);

    // bow_logits = delta @ bow_W  (B direct from global, no LDS transpose)
    mm_bow<<<dim3((NVOCAB+63)/64), dim3(256), 0, stream>>>(deltaB, bowW, o_bow);
}